// Round 16
// baseline (145.094 us; speedup 1.0000x reference)
//
#include <hip/hip_runtime.h>

static constexpr int IN_F = 256;
static constexpr int OUT_F = 128;
static constexpr int BM = 64, BK = 32;
static constexpr int NTK = IN_F / BK;  // 8 K-tiles

using bf16x4 = __attribute__((ext_vector_type(4))) __bf16;
using bf16x8 = __attribute__((ext_vector_type(8))) __bf16;
using f32x4 = __attribute__((ext_vector_type(4))) float;

// k-permutation: fragment split-halves made contiguous.
__device__ __host__ __forceinline__ int kperm(int kl) {
  return (((kl >> 2) & 3) << 3) + ((kl >> 4) << 2) + (kl & 3);
}

// ---------------------------------------------------------------------------
// Fused setup: blocks [0,128) convert W -> bf16 hi/lo transposed+k-permuted;
// blocks [128, 128+196) zero deg. Saves one dispatch.
// ---------------------------------------------------------------------------
__global__ __launch_bounds__(256) void wconv_zero_kernel(
    const float* __restrict__ W, __bf16* __restrict__ WTh,
    __bf16* __restrict__ WTl, int* __restrict__ deg, int M) {
  if ((int)blockIdx.x < 128) {
    const int idx = (int)blockIdx.x * 256 + (int)threadIdx.x;  // 0..32767
    const int k = idx >> 7;
    const int n = idx & 127;
    const float w = W[idx];
    const __bf16 hi = (__bf16)w;
    const __bf16 lo = (__bf16)(w - (float)hi);
    const int kk = (k & ~31) + kperm(k & 31);
    WTh[n * 256 + kk] = hi;
    WTl[n * 256 + kk] = lo;
  } else {
    const int i = ((int)blockIdx.x - 128) * 256 + (int)threadIdx.x;
    if (i < M) deg[i] = 0;
  }
}

// ---------------------------------------------------------------------------
// Histogram standalone (NO LDS -> full occupancy): deg counts + slot in tmp.
// ---------------------------------------------------------------------------
__global__ __launch_bounds__(256) void hist_kernel(
    const int* __restrict__ dst, int* __restrict__ deg, int* __restrict__ tmp,
    int E) {
  const int e = (int)blockIdx.x * 256 + (int)threadIdx.x;
  if (e < E) {
    const int s = atomicAdd(&deg[dst[e]], 1);
    if (tmp) tmp[e] = s;
  }
}

// ---------------------------------------------------------------------------
// Fused: blocks [0, gemmBlocks): split-bf16 MFMA GEMM (r15 proven).
// Blocks >= gemmBlocks: placement (NO atomics): pay[off[dst]+tmp] = (src,val)
// -- hides under the GEMM.
// ---------------------------------------------------------------------------
__global__ __launch_bounds__(256) void gemm_place_kernel(
    const float* __restrict__ X, const __bf16* __restrict__ WTh,
    const __bf16* __restrict__ WTl, const float* __restrict__ bias,
    float* __restrict__ H, int M, const int* __restrict__ dst,
    const int* __restrict__ src, const float* __restrict__ vals,
    const int* __restrict__ off, const int* __restrict__ tmp,
    int2* __restrict__ pay, int E, int gemmBlocks) {
  if ((int)blockIdx.x >= gemmBlocks) {
    if (pay) {
      const int e = ((int)blockIdx.x - gemmBlocks) * 256 + (int)threadIdx.x;
      if (e < E) {
        const int pos = off[dst[e]] + tmp[e];
        pay[pos] = make_int2(src[e], __float_as_int(vals[e]));
      }
    }
    return;
  }

  __shared__ __bf16 Ah[64][40], Al[64][40];
  __shared__ __bf16 Bh[128][40], Bl[128][40];  // total 30720 B

  const int tid = threadIdx.x;
  const int wid = tid >> 6;
  const int lane = tid & 63;
  const int h = lane >> 4;
  const int fr = lane & 15;
  const int row0 = (int)blockIdx.x * BM;

  const int ar = tid >> 3;
  const int ac4 = (tid & 7) << 2;
  const int akp = kperm(ac4);
  const int bcol = tid >> 1;
  const int bseg0 = (tid & 1) << 1;

  f32x4 acc[8];
#pragma unroll
  for (int c = 0; c < 8; ++c) acc[c] = (f32x4){0.f, 0.f, 0.f, 0.f};

  const float4 fz = make_float4(0.f, 0.f, 0.f, 0.f);
  const int gr0 = row0 + ar;
  const int gr1 = row0 + ar + 32;

  float4 pA0 = (gr0 < M) ? *(const float4*)(X + (size_t)gr0 * IN_F + ac4) : fz;
  float4 pA1 = (gr1 < M) ? *(const float4*)(X + (size_t)gr1 * IN_F + ac4) : fz;
  bf16x8 pBh0 = *(const bf16x8*)(WTh + bcol * 256 + 8 * bseg0);
  bf16x8 pBh1 = *(const bf16x8*)(WTh + bcol * 256 + 8 * bseg0 + 8);
  bf16x8 pBl0 = *(const bf16x8*)(WTl + bcol * 256 + 8 * bseg0);
  bf16x8 pBl1 = *(const bf16x8*)(WTl + bcol * 256 + 8 * bseg0 + 8);

#pragma unroll 1
  for (int t = 0; t < NTK; ++t) {
    {
      float a0[4] = {pA0.x, pA0.y, pA0.z, pA0.w};
      float a1[4] = {pA1.x, pA1.y, pA1.z, pA1.w};
      bf16x4 h0, l0, h1, l1;
#pragma unroll
      for (int j = 0; j < 4; ++j) {
        h0[j] = (__bf16)a0[j];
        l0[j] = (__bf16)(a0[j] - (float)h0[j]);
        h1[j] = (__bf16)a1[j];
        l1[j] = (__bf16)(a1[j] - (float)h1[j]);
      }
      *(bf16x4*)&Ah[ar][akp] = h0;
      *(bf16x4*)&Al[ar][akp] = l0;
      *(bf16x4*)&Ah[ar + 32][akp] = h1;
      *(bf16x4*)&Al[ar + 32][akp] = l1;
      *(bf16x8*)&Bh[bcol][8 * bseg0] = pBh0;
      *(bf16x8*)&Bh[bcol][8 * bseg0 + 8] = pBh1;
      *(bf16x8*)&Bl[bcol][8 * bseg0] = pBl0;
      *(bf16x8*)&Bl[bcol][8 * bseg0 + 8] = pBl1;
    }
    __syncthreads();

    if (t + 1 < NTK) {
      const int k0 = (t + 1) * BK;
      pA0 = (gr0 < M) ? *(const float4*)(X + (size_t)gr0 * IN_F + k0 + ac4) : fz;
      pA1 = (gr1 < M) ? *(const float4*)(X + (size_t)gr1 * IN_F + k0 + ac4) : fz;
      pBh0 = *(const bf16x8*)(WTh + bcol * 256 + k0 + 8 * bseg0);
      pBh1 = *(const bf16x8*)(WTh + bcol * 256 + k0 + 8 * bseg0 + 8);
      pBl0 = *(const bf16x8*)(WTl + bcol * 256 + k0 + 8 * bseg0);
      pBl1 = *(const bf16x8*)(WTl + bcol * 256 + k0 + 8 * bseg0 + 8);
    }

    const bf16x8 fah = *(const bf16x8*)&Ah[16 * wid + fr][8 * h];
    const bf16x8 fal = *(const bf16x8*)&Al[16 * wid + fr][8 * h];
#pragma unroll
    for (int ct = 0; ct < 8; ++ct) {
      const bf16x8 fbh = *(const bf16x8*)&Bh[ct * 16 + fr][8 * h];
      const bf16x8 fbl = *(const bf16x8*)&Bl[ct * 16 + fr][8 * h];
      acc[ct] =
          __builtin_amdgcn_mfma_f32_16x16x32_bf16(fah, fbh, acc[ct], 0, 0, 0);
      acc[ct] =
          __builtin_amdgcn_mfma_f32_16x16x32_bf16(fah, fbl, acc[ct], 0, 0, 0);
      acc[ct] =
          __builtin_amdgcn_mfma_f32_16x16x32_bf16(fal, fbh, acc[ct], 0, 0, 0);
    }
    __syncthreads();
  }

  const int rbase = row0 + 16 * wid + 4 * h;
#pragma unroll
  for (int ct = 0; ct < 8; ++ct) {
    const int col = ct * 16 + fr;
    const float bv = bias[col];
#pragma unroll
    for (int r = 0; r < 4; ++r) {
      const int gr = rbase + r;
      if (gr < M) H[(size_t)gr * OUT_F + col] = acc[ct][r] + bv;
    }
  }
}

// ---------------------------------------------------------------------------
// Hierarchical exclusive scan of deg[n] -> off[n+1]; optional cursor=off copy.
// ---------------------------------------------------------------------------
__global__ __launch_bounds__(256) void scan_partial_kernel(
    const int* __restrict__ deg, int* __restrict__ bsum, int n) {
  __shared__ int red[256];
  const int i = (int)blockIdx.x * 256 + (int)threadIdx.x;
  red[threadIdx.x] = (i < n) ? deg[i] : 0;
  __syncthreads();
  for (int s = 128; s > 0; s >>= 1) {
    if ((int)threadIdx.x < s) red[threadIdx.x] += red[threadIdx.x + s];
    __syncthreads();
  }
  if (threadIdx.x == 0) bsum[blockIdx.x] = red[0];
}

__global__ __launch_bounds__(256) void scan_base_kernel(
    const int* __restrict__ bsum, int* __restrict__ bbase, int nb) {
  __shared__ int sh[256];
  const int t = threadIdx.x;
  const int x = (t < nb) ? bsum[t] : 0;
  sh[t] = x;
  __syncthreads();
  for (int d = 1; d < 256; d <<= 1) {
    const int v = (t >= d) ? sh[t - d] : 0;
    __syncthreads();
    sh[t] += v;
    __syncthreads();
  }
  if (t < nb) bbase[t] = sh[t] - x;  // exclusive
}

__global__ __launch_bounds__(256) void scan_write_kernel(
    const int* __restrict__ deg, const int* __restrict__ bbase,
    int* __restrict__ off, int* __restrict__ cursor, int n) {
  const int i = (int)blockIdx.x * 256 + (int)threadIdx.x;
  const int lane = threadIdx.x & 63;
  const int w = threadIdx.x >> 6;
  const int x = (i < n) ? deg[i] : 0;
  int inc = x;
#pragma unroll
  for (int d = 1; d < 64; d <<= 1) {
    const int t = __shfl_up(inc, d, 64);
    if (lane >= d) inc += t;
  }
  __shared__ int wsum[4];
  if (lane == 63) wsum[w] = inc;
  __syncthreads();
  int wb = 0;
#pragma unroll
  for (int k = 0; k < 4; ++k) wb += (k < w) ? wsum[k] : 0;
  const int excl = bbase[blockIdx.x] + wb + inc - x;
  if (i < n) {
    off[i] = excl;
    if (cursor) cursor[i] = excl;
    if (i == n - 1) off[n] = excl + x;
  }
}

// Fallback scatters (atomic cursor).
__global__ __launch_bounds__(256) void scatter_pay_kernel(
    const int* __restrict__ dst, const int* __restrict__ src,
    const float* __restrict__ vals, int* __restrict__ cursor,
    int2* __restrict__ pay, int E) {
  const int e = (int)blockIdx.x * 256 + (int)threadIdx.x;
  if (e < E) {
    const int pos = atomicAdd(&cursor[dst[e]], 1);
    pay[pos] = make_int2(src[e], __float_as_int(vals[e]));
  }
}

__global__ __launch_bounds__(256) void scatter_perm_kernel(
    const int* __restrict__ dst, int* __restrict__ cursor,
    int* __restrict__ perm, int E) {
  const int e = (int)blockIdx.x * 256 + (int)threadIdx.x;
  if (e < E) {
    const int pos = atomicAdd(&cursor[dst[e]], 1);
    perm[pos] = e;
  }
}

// ---------------------------------------------------------------------------
// Gather: one 64-lane wave per node; 16 independent H-row loads in flight.
// ---------------------------------------------------------------------------
__device__ __forceinline__ float2 h_row2(const float* __restrict__ H, int s,
                                         int lane) {
  return reinterpret_cast<const float2*>(H + (size_t)s * OUT_F)[lane];
}

template <bool PAYLOAD>
__device__ __forceinline__ void gather_body(
    const float* __restrict__ H, const int2* __restrict__ pay,
    const float* __restrict__ vals, const int* __restrict__ src,
    const int* __restrict__ perm, const int* __restrict__ off,
    float* __restrict__ out, int wave, int lane) {
  const int b = off[wave];
  const int e = off[wave + 1];
  float accx = 0.f, accy = 0.f;

  for (int base = b; base < e; base += 64) {
    const int n = min(64, e - base);
    int s = 0;
    float v = 0.f;
    if (lane < n) {
      if (PAYLOAD) {
        const int2 p = pay[base + lane];
        s = p.x;
        v = __int_as_float(p.y);
      } else {
        const int id = perm[base + lane];
        v = vals[id];
        s = src[id];
      }
    }
    int k = 0;
    for (; k + 16 <= n; k += 16) {
      int sj[16];
      float2 hj[16];
      float vj[16];
#pragma unroll
      for (int j = 0; j < 16; ++j) sj[j] = __shfl(s, k + j, 64);
#pragma unroll
      for (int j = 0; j < 16; ++j) hj[j] = h_row2(H, sj[j], lane);
#pragma unroll
      for (int j = 0; j < 16; ++j) vj[j] = __shfl(v, k + j, 64);
#pragma unroll
      for (int j = 0; j < 16; ++j) {
        accx = fmaf(vj[j], hj[j].x, accx);
        accy = fmaf(vj[j], hj[j].y, accy);
      }
    }
    for (; k + 8 <= n; k += 8) {
      int sj[8];
      float2 hj[8];
      float vj[8];
#pragma unroll
      for (int j = 0; j < 8; ++j) sj[j] = __shfl(s, k + j, 64);
#pragma unroll
      for (int j = 0; j < 8; ++j) hj[j] = h_row2(H, sj[j], lane);
#pragma unroll
      for (int j = 0; j < 8; ++j) vj[j] = __shfl(v, k + j, 64);
#pragma unroll
      for (int j = 0; j < 8; ++j) {
        accx = fmaf(vj[j], hj[j].x, accx);
        accy = fmaf(vj[j], hj[j].y, accy);
      }
    }
    for (; k < n; ++k) {
      const int sk = __shfl(s, k, 64);
      const float vk = __shfl(v, k, 64);
      const float2 hv = h_row2(H, sk, lane);
      accx = fmaf(vk, hv.x, accx);
      accy = fmaf(vk, hv.y, accy);
    }
  }
  float2 o;
  o.x = accx;
  o.y = accy;
  reinterpret_cast<float2*>(out + (size_t)wave * OUT_F)[lane] = o;
}

__global__ __launch_bounds__(256) void gather_pay_kernel(
    const float* __restrict__ H, const int2* __restrict__ pay,
    const int* __restrict__ off, float* __restrict__ out, int M) {
  const int wave = (int)((blockIdx.x * blockDim.x + threadIdx.x) >> 6);
  const int lane = threadIdx.x & 63;
  if (wave >= M) return;
  gather_body<true>(H, pay, nullptr, nullptr, nullptr, off, out, wave, lane);
}

__global__ __launch_bounds__(256) void gather_perm_kernel(
    const float* __restrict__ H, const float* __restrict__ vals,
    const int* __restrict__ src, const int* __restrict__ off,
    const int* __restrict__ perm, float* __restrict__ out, int M) {
  const int wave = (int)((blockIdx.x * blockDim.x + threadIdx.x) >> 6);
  const int lane = threadIdx.x & 63;
  if (wave >= M) return;
  gather_body<false>(H, nullptr, vals, src, perm, off, out, wave, lane);
}

// ---------------------------------------------------------------------------
extern "C" void kernel_launch(void* const* d_in, const int* in_sizes, int n_in,
                              void* d_out, int out_size, void* d_ws,
                              size_t ws_size, hipStream_t stream) {
  const float* X = (const float*)d_in[0];        // [M, 256]
  const float* W = (const float*)d_in[1];        // [256, 128]
  const float* bias = (const float*)d_in[2];     // [128]
  const float* adj_vals = (const float*)d_in[3]; // [E]
  const int* edge_src = (const int*)d_in[4];     // [E]
  const int* edge_dst = (const int*)d_in[5];     // [E]
  float* out = (float*)d_out;                    // [M, 128]

  const int M = in_sizes[0] / IN_F;  // 50000
  const int E = in_sizes[3];         // 800000

  char* ws = (char*)d_ws;
  size_t o = 0;
  auto take = [&](size_t bytes) {
    void* p = ws + o;
    o = (o + bytes + 15) & ~(size_t)15;
    return p;
  };
  float* H = (float*)take((size_t)M * OUT_F * sizeof(float));  // 25.6 MB
  int* off = (int*)take((size_t)(M + 1) * sizeof(int));
  int* deg = (int*)take((size_t)M * sizeof(int));
  __bf16* WTh = (__bf16*)take((size_t)OUT_F * IN_F * sizeof(__bf16));  // 64 KB
  __bf16* WTl = (__bf16*)take((size_t)OUT_F * IN_F * sizeof(__bf16));  // 64 KB
  const int nb = (M + 255) / 256;  // 196 (<= 256)
  const size_t scanb = 2 * (((size_t)nb * sizeof(int) + 15) & ~(size_t)15);

  // Tier select by ws budget (deterministic).
  const size_t base = o;
  const size_t need_primary = base + ((size_t)E + M) * sizeof(int) +
                              (size_t)E * sizeof(int2) + scanb + 64;
  const size_t need_fb1 =
      base + (size_t)M * sizeof(int) + (size_t)E * sizeof(int2) + scanb + 64;
  const int tier = (ws_size == 0 || need_primary <= ws_size) ? 0
                   : (need_fb1 <= ws_size)                   ? 1
                                                             : 2;

  int *tmp = nullptr, *cursor = nullptr, *perm = nullptr;
  int2* pay = nullptr;
  if (tier == 0) {
    tmp = (int*)take((size_t)E * sizeof(int));
    pay = (int2*)take((size_t)E * sizeof(int2));
  } else if (tier == 1) {
    cursor = (int*)take((size_t)M * sizeof(int));
    pay = (int2*)take((size_t)E * sizeof(int2));
  } else {
    cursor = (int*)take((size_t)M * sizeof(int));
    perm = (int*)take((size_t)E * sizeof(int));
  }
  int* bsum = (int*)take((size_t)nb * sizeof(int));
  int* bbase = (int*)take((size_t)nb * sizeof(int));

  // Setup: W conversion + deg zeroing in one dispatch.
  wconv_zero_kernel<<<128 + nb, 256, 0, stream>>>(W, WTh, WTl, deg, M);

  const int eb = (E + 255) / 256;  // 3125
  // Histogram standalone (no LDS, full occupancy).
  hist_kernel<<<eb, 256, 0, stream>>>(edge_dst, deg,
                                      (tier == 0) ? tmp : nullptr, E);

  scan_partial_kernel<<<nb, 256, 0, stream>>>(deg, bsum, M);
  scan_base_kernel<<<1, 256, 0, stream>>>(bsum, bbase, nb);
  scan_write_kernel<<<nb, 256, 0, stream>>>(deg, bbase, off, cursor, M);

  const int gemmBlocks = (M + BM - 1) / BM;  // 782
  dim3 gather_grid((M + 3) / 4);  // 4 waves (256 threads) per block

  if (tier == 0) {
    // GEMM fused with atomic-free placement (place hides under GEMM).
    gemm_place_kernel<<<gemmBlocks + eb, 256, 0, stream>>>(
        X, WTh, WTl, bias, H, M, edge_dst, edge_src, adj_vals, off, tmp, pay,
        E, gemmBlocks);
    gather_pay_kernel<<<gather_grid, 256, 0, stream>>>(H, pay, off, out, M);
  } else {
    // Fallback: GEMM alone, then atomic scatter.
    gemm_place_kernel<<<gemmBlocks, 256, 0, stream>>>(
        X, WTh, WTl, bias, H, M, nullptr, nullptr, nullptr, nullptr, nullptr,
        nullptr, 0, gemmBlocks);
    if (tier == 1) {
      scatter_pay_kernel<<<eb, 256, 0, stream>>>(edge_dst, edge_src, adj_vals,
                                                 cursor, pay, E);
      gather_pay_kernel<<<gather_grid, 256, 0, stream>>>(H, pay, off, out, M);
    } else {
      scatter_perm_kernel<<<eb, 256, 0, stream>>>(edge_dst, cursor, perm, E);
      gather_perm_kernel<<<gather_grid, 256, 0, stream>>>(H, adj_vals, edge_src,
                                                          off, perm, out, M);
    }
  }
}